// Round 8
// baseline (182.511 us; speedup 1.0000x reference)
//
#include <hip/hip_runtime.h>

#define EPSV 1e-5f
#define NBINS 32

typedef unsigned short u16;
typedef unsigned int u32;
typedef __attribute__((ext_vector_type(4))) unsigned short ush4;
typedef __attribute__((ext_vector_type(8))) unsigned short ush8;
typedef __attribute__((ext_vector_type(8))) short short8;
typedef __attribute__((ext_vector_type(4))) float f32x4;

__device__ __forceinline__ float relu(float x) { return fmaxf(x, 0.f); }

__device__ __forceinline__ u16 f2bf(float f) {
    u32 u = __builtin_bit_cast(u32, f);
    u32 r = (u + 0x7fffu + ((u >> 16) & 1u)) >> 16;
    return (u16)r;
}
__device__ __forceinline__ float bf2f(u16 v) {
    return __builtin_bit_cast(float, (u32)v << 16);
}

// ---- prep: zero stat bins + swizzle pw weights into fragment order ----
template<int CIN, int COUT>
__device__ __forceinline__ void prep_one(const float* __restrict__ w,
                                         u16* __restrict__ dst, int widx) {
    const int NT = COUT / 16;
    int lane = widx & 63;
    int t  = (widx >> 6) % NT;
    int ks = (widx >> 6) / NT;
    int co  = t * 16 + (lane & 15);
    int ci0 = ks * 32 + (lane >> 4) * 8;
#pragma unroll
    for (int i = 0; i < 8; i++)
        dst[(size_t)widx * 8 + i] = f2bf(w[co * CIN + ci0 + i]);
}

__global__ void prep_k(const float* __restrict__ w0, const float* __restrict__ w1,
                       const float* __restrict__ w2, u16* __restrict__ s0,
                       u16* __restrict__ s1, u16* __restrict__ s2,
                       float* __restrict__ bins) {
    int i = blockIdx.x * 256 + threadIdx.x;          // 3328 threads
    for (int z = i; z < 6 * 2 * NBINS * 128; z += 3328) bins[z] = 0.f;
    if (i < 256)       prep_one<32, 64>  (w0, s0, i);
    else if (i < 1280) prep_one<64, 128> (w1, s1, i - 256);
    else if (i < 3328) prep_one<128, 128>(w2, s2, i - 1280);
}

// ---- depthwise 3x3 pad 1 stride 1, LDS-staged band, fused finalize+stats ----
template<int IHW, int C, bool BNIN, int BR, int LST, typename TIN>
__global__ __launch_bounds__(256) void dwlds_k(
    const TIN* __restrict__ in, u16* __restrict__ out,
    const float* __restrict__ w9, const float* __restrict__ bias,
    const float* __restrict__ gamma, const float* __restrict__ beta,
    const float* __restrict__ bsum_in, const float* __restrict__ bsq_in,
    float invcnt_in, float* __restrict__ bsum, float* __restrict__ bsq)
{
    constexpr bool F32 = sizeof(TIN) == 4;
    constexpr int NB  = IHW / BR;
    constexpr int TPR = IHW / 8;
    constexpr int NACT = BR * TPR;
    constexpr int W4 = IHW / 4;
    __shared__ float tile[(BR + 2) * LST];
    __shared__ float bnss[2];
    __shared__ float redbuf[8];

    const int bid = blockIdx.x;
    const int plane = bid / NB;
    const int band  = bid % NB;
    const int c = plane & (C - 1);
    const int tid = threadIdx.x;

    if (BNIN) {
        if (tid < NBINS) {
            float s = bsum_in[tid * C + c];
            float q = bsq_in [tid * C + c];
#pragma unroll
            for (int m = NBINS / 2; m >= 1; m >>= 1) {
                s += __shfl_xor(s, m); q += __shfl_xor(q, m);
            }
            if (tid == 0) {
                float mm  = s * invcnt_in;
                float var = fmaf(q, invcnt_in, -mm * mm);
                float is  = gamma[c] * rsqrtf(var + EPSV);
                bnss[0] = is; bnss[1] = fmaf(-mm, is, beta[c]);
            }
        }
        __syncthreads();
    }
    const float scv = BNIN ? bnss[0] : 1.f;
    const float shv = BNIN ? bnss[1] : 0.f;

    const int r0 = band * BR;
    const TIN* base = in + (size_t)plane * (IHW * IHW);

    for (int i = tid; i < (BR + 2) * 2; i += 256) {
        int r = i >> 1, side = i & 1;
        float4 z = {0.f, 0.f, 0.f, 0.f};
        *(float4*)&tile[r * LST + side * (IHW + 4)] = z;
    }
    for (int i = tid; i < (BR + 2) * W4; i += 256) {
        int r = i / W4, c4 = (i % W4) * 4;
        int gr = r0 - 1 + r;
        float4 v = {0.f, 0.f, 0.f, 0.f};
        if (gr >= 0 && gr < IHW) {
            if constexpr (F32) {
                v = *(const float4*)(base + (size_t)gr * IHW + c4);
            } else {
                ush4 h = *(const ush4*)(base + (size_t)gr * IHW + c4);
                v = {bf2f(h[0]), bf2f(h[1]), bf2f(h[2]), bf2f(h[3])};
            }
            if (BNIN) {
                v.x = relu(fmaf(v.x, scv, shv)); v.y = relu(fmaf(v.y, scv, shv));
                v.z = relu(fmaf(v.z, scv, shv)); v.w = relu(fmaf(v.w, scv, shv));
            }
        }
        *(float4*)&tile[r * LST + 4 + c4] = v;
    }
    __syncthreads();

    float s = 0.f, q = 0.f;
    if (tid < NACT) {
        const int r  = tid / TPR;
        const int c0 = (tid % TPR) * 8;
        float wv[9];
#pragma unroll
        for (int k = 0; k < 9; k++) wv[k] = w9[c * 9 + k];
        float bz = bias[c];
        float a[8];
#pragma unroll
        for (int j = 0; j < 8; j++) a[j] = bz;
#pragma unroll
        for (int kr = 0; kr < 3; kr++) {
            const float* rp = &tile[(r + kr) * LST + 3 + c0];
            float v[10];
#pragma unroll
            for (int i = 0; i < 10; i++) v[i] = rp[i];
#pragma unroll
            for (int j = 0; j < 8; j++)
                a[j] = fmaf(wv[kr * 3], v[j],
                        fmaf(wv[kr * 3 + 1], v[j + 1],
                         fmaf(wv[kr * 3 + 2], v[j + 2], a[j])));
        }
        u16* ob = out + (size_t)plane * (IHW * IHW) + (size_t)(r0 + r) * IHW + c0;
        ush4 o0 = {f2bf(a[0]), f2bf(a[1]), f2bf(a[2]), f2bf(a[3])};
        ush4 o1 = {f2bf(a[4]), f2bf(a[5]), f2bf(a[6]), f2bf(a[7])};
        *(ush4*)ob = o0;
        *(ush4*)(ob + 4) = o1;
#pragma unroll
        for (int j = 0; j < 8; j++) { s += a[j]; q = fmaf(a[j], a[j], q); }
    }
#pragma unroll
    for (int m = 32; m >= 1; m >>= 1) { s += __shfl_xor(s, m); q += __shfl_xor(q, m); }
    int lane = tid & 63, wid = tid >> 6;
    if (lane == 0) { redbuf[wid] = s; redbuf[4 + wid] = q; }
    __syncthreads();
    if (tid == 0) {
        s = redbuf[0] + redbuf[1] + redbuf[2] + redbuf[3];
        q = redbuf[4] + redbuf[5] + redbuf[6] + redbuf[7];
        unsigned bin = bid & (NBINS - 1);
        atomicAdd(&bsum[bin * C + c], s);
        atomicAdd(&bsq [bin * C + c], q);
    }
}

// ---- depthwise 3x3 pad 1 STRIDE 2, LDS-staged band, fused finalize+stats ----
// Block = (plane, band of BRO=14 output rows). Stage 29 x IHW input floats
// (BN+ReLU at stage time), compute 4 px/thread from LDS via aligned float4.
template<int IHW, int OHW, int C>
__global__ __launch_bounds__(256) void dwlds2_k(
    const u16* __restrict__ in, u16* __restrict__ out,
    const float* __restrict__ w9, const float* __restrict__ bias,
    const float* __restrict__ gamma, const float* __restrict__ beta,
    const float* __restrict__ bsum_in, const float* __restrict__ bsq_in,
    float invcnt_in, float* __restrict__ bsum, float* __restrict__ bsq)
{
    constexpr int BRO = 14;                 // output rows per block
    constexpr int NB  = OHW / BRO;          // 4 bands
    constexpr int NIR = 2 * BRO + 1;        // 29 staged input rows
    constexpr int LST = 120;                // row stride in LDS floats
    constexpr int CT  = OHW / 4;            // 14 col tiles
    constexpr int NACT = BRO * CT;          // 196 compute threads
    constexpr int W4 = IHW / 4;             // 28
    __shared__ float tile[NIR * LST];
    __shared__ float bnss[2];
    __shared__ float redbuf[8];

    const int bid = blockIdx.x;
    const int plane = bid / NB;
    const int band  = bid % NB;
    const int c = plane & (C - 1);
    const int tid = threadIdx.x;

    if (tid < NBINS) {
        float s = bsum_in[tid * C + c];
        float q = bsq_in [tid * C + c];
#pragma unroll
        for (int m = NBINS / 2; m >= 1; m >>= 1) {
            s += __shfl_xor(s, m); q += __shfl_xor(q, m);
        }
        if (tid == 0) {
            float mm  = s * invcnt_in;
            float var = fmaf(q, invcnt_in, -mm * mm);
            float is  = gamma[c] * rsqrtf(var + EPSV);
            bnss[0] = is; bnss[1] = fmaf(-mm, is, beta[c]);
        }
    }
    __syncthreads();
    const float scv = bnss[0], shv = bnss[1];

    const int r0 = band * BRO;              // first output row
    const u16* base = in + (size_t)plane * (IHW * IHW);

    // zero left pad (cols 0..3 of each staged row)
    for (int i = tid; i < NIR; i += 256) {
        float4 z = {0.f, 0.f, 0.f, 0.f};
        *(float4*)&tile[i * LST] = z;
    }
    // stage input rows 2*r0-1 .. 2*r0+27 with BN+ReLU
    for (int i = tid; i < NIR * W4; i += 256) {
        int lr = i / W4, c4 = (i % W4) * 4;
        int gr = 2 * r0 - 1 + lr;
        float4 v = {0.f, 0.f, 0.f, 0.f};
        if (gr >= 0 && gr < IHW) {
            ush4 h = *(const ush4*)(base + (size_t)gr * IHW + c4);
            v.x = relu(fmaf(bf2f(h[0]), scv, shv));
            v.y = relu(fmaf(bf2f(h[1]), scv, shv));
            v.z = relu(fmaf(bf2f(h[2]), scv, shv));
            v.w = relu(fmaf(bf2f(h[3]), scv, shv));
        }
        *(float4*)&tile[lr * LST + 4 + c4] = v;
    }
    __syncthreads();

    float s = 0.f, q = 0.f;
    if (tid < NACT) {
        const int r  = tid / CT;            // output row in band
        const int ct = tid % CT;            // 4-px col tile
        float wv[9];
#pragma unroll
        for (int k = 0; k < 9; k++) wv[k] = w9[c * 9 + k];
        float bz = bias[c];
        float a[4] = {bz, bz, bz, bz};
#pragma unroll
        for (int kr = 0; kr < 3; kr++) {
            // staged row 2r+kr; need input cols 8ct-1 .. 8ct+7 -> tc 3+8ct..11+8ct
            const float* rp = &tile[(2 * r + kr) * LST + 8 * ct];
            float4 va = *(const float4*)rp;        // tc 8ct+0..3 (cols 8ct-4..-1)
            float4 vb = *(const float4*)(rp + 4);  // cols 8ct..8ct+3
            float4 vc = *(const float4*)(rp + 8);  // cols 8ct+4..8ct+7
            float sq[9] = {va.w, vb.x, vb.y, vb.z, vb.w, vc.x, vc.y, vc.z, vc.w};
            float k0 = wv[kr * 3], k1 = wv[kr * 3 + 1], k2 = wv[kr * 3 + 2];
#pragma unroll
            for (int cc = 0; cc < 4; cc++)
                a[cc] = fmaf(k0, sq[2 * cc], fmaf(k1, sq[2 * cc + 1],
                            fmaf(k2, sq[2 * cc + 2], a[cc])));
        }
        u16* ob = out + (size_t)plane * (OHW * OHW) + (size_t)(r0 + r) * OHW + 4 * ct;
        ush4 o = {f2bf(a[0]), f2bf(a[1]), f2bf(a[2]), f2bf(a[3])};
        *(ush4*)ob = o;
#pragma unroll
        for (int j = 0; j < 4; j++) { s += a[j]; q = fmaf(a[j], a[j], q); }
    }
#pragma unroll
    for (int m = 32; m >= 1; m >>= 1) { s += __shfl_xor(s, m); q += __shfl_xor(q, m); }
    int lane = tid & 63, wid = tid >> 6;
    if (lane == 0) { redbuf[wid] = s; redbuf[4 + wid] = q; }
    __syncthreads();
    if (tid == 0) {
        s = redbuf[0] + redbuf[1] + redbuf[2] + redbuf[3];
        q = redbuf[4] + redbuf[5] + redbuf[6] + redbuf[7];
        unsigned bin = bid & (NBINS - 1);
        atomicAdd(&bsum[bin * C + c], s);
        atomicAdd(&bsq [bin * C + c], q);
    }
}

// ---- pointwise 1x1 conv via bf16 MFMA (X=A, W=B), folded finalize + stats ----
template<int CIN, int COUT, int HW>
__global__ __launch_bounds__(256, 4) void pwmfma_k(
    const u16* __restrict__ in, u16* __restrict__ out,
    const u16* __restrict__ wswz, const float* __restrict__ bias,
    const float* __restrict__ gamma, const float* __restrict__ beta,
    const float* __restrict__ bsum_in, const float* __restrict__ bsq_in,
    float invcnt_in, float* __restrict__ bsum, float* __restrict__ bsq)
{
    constexpr int NK = CIN / 32;
    constexpr int NT = COUT / 16;
    constexpr int ROWSTRIDE = NK * 512 + 8;
    __shared__ u16 frag[4 * ROWSTRIDE];
    __shared__ float lsum[4 * COUT];
    __shared__ float lsq [4 * COUT];
    __shared__ float scs[CIN], shs[CIN];

    const int tid = threadIdx.x;

    if (tid < CIN) {
        float s = 0.f, q = 0.f;
        for (int b = 0; b < NBINS; b++) {
            s += bsum_in[b * CIN + tid];
            q += bsq_in [b * CIN + tid];
        }
        float mm  = s * invcnt_in;
        float var = fmaf(q, invcnt_in, -mm * mm);
        float is  = gamma[tid] * rsqrtf(var + EPSV);
        scs[tid] = is; shs[tid] = fmaf(-mm, is, beta[tid]);
    }
    __syncthreads();

    const size_t pixbase = (size_t)blockIdx.x * 64;   // HW % 64 == 0
    const int n  = (int)(pixbase / HW);
    const int p0 = (int)(pixbase % HW);

    {
        const int px = tid & 63;
        const int kq = tid >> 6;
        const u16* ipx = in + (size_t)n * CIN * HW + p0 + px;
#pragma unroll
        for (int ks = 0; ks < NK; ks++) {
            const int ci0 = (ks * 4 + kq) * 8;
            short8 pkd;
#pragma unroll
            for (int j = 0; j < 8; j++) {
                float v = relu(fmaf(bf2f(ipx[(size_t)(ci0 + j) * HW]), scs[ci0 + j], shs[ci0 + j]));
                pkd[j] = (short)f2bf(v);
            }
            *(short8*)&frag[(size_t)(px >> 4) * ROWSTRIDE + ks * 512 + ((px & 15) + 16 * kq) * 8] = pkd;
        }
    }
    __syncthreads();

    const int wv   = tid >> 6;
    const int lane = tid & 63;
    f32x4 acc[NT];
#pragma unroll
    for (int t = 0; t < NT; t++) acc[t] = (f32x4){0.f, 0.f, 0.f, 0.f};

    const short8* wp = (const short8*)wswz;
#pragma unroll
    for (int ks = 0; ks < NK; ks++) {
        short8 af = *(const short8*)&frag[(size_t)wv * ROWSTRIDE + ks * 512 + lane * 8];
#pragma unroll
        for (int t = 0; t < NT; t++) {
            short8 bf = wp[(ks * NT + t) * 64 + lane];
            acc[t] = __builtin_amdgcn_mfma_f32_16x16x32_bf16(af, bf, acc[t], 0, 0, 0);
        }
    }

    const int col  = lane & 15;
    const int prow = (lane >> 4) * 4;
    const int p    = p0 + wv * 16 + prow;
#pragma unroll
    for (int t = 0; t < NT; t++) {
        int co = t * 16 + col;
        float bz = bias[co];
        float v0 = acc[t][0] + bz, v1 = acc[t][1] + bz;
        float v2 = acc[t][2] + bz, v3 = acc[t][3] + bz;
        ush4 o = {f2bf(v0), f2bf(v1), f2bf(v2), f2bf(v3)};
        *(ush4*)(out + ((size_t)n * COUT + co) * HW + p) = o;
        float s = (v0 + v1) + (v2 + v3);
        float q = fmaf(v0, v0, fmaf(v1, v1, fmaf(v2, v2, v3 * v3)));
        s += __shfl_xor(s, 16); q += __shfl_xor(q, 16);
        s += __shfl_xor(s, 32); q += __shfl_xor(q, 32);
        if (lane < 16) { lsum[wv * COUT + co] = s; lsq[wv * COUT + co] = q; }
    }
    __syncthreads();
    if (tid < COUT) {
        const unsigned bin = blockIdx.x & (NBINS - 1);
        float s = lsum[tid] + lsum[COUT + tid] + lsum[2 * COUT + tid] + lsum[3 * COUT + tid];
        float q = lsq[tid]  + lsq[COUT + tid]  + lsq[2 * COUT + tid]  + lsq[3 * COUT + tid];
        atomicAdd(&bsum[bin * COUT + tid], s);
        atomicAdd(&bsq [bin * COUT + tid], q);
    }
}

// ---- final: folded finalize + BN+ReLU + global average pool ----
template<int HW, int C>
__global__ __launch_bounds__(256) void avgpool_k(
    const u16* __restrict__ t,
    const float* __restrict__ gamma, const float* __restrict__ beta,
    const float* __restrict__ bsum_in, const float* __restrict__ bsq_in,
    float invcnt_in, float* __restrict__ out)
{
    __shared__ float bnss[2];
    __shared__ float red[4];
    int nc = blockIdx.x;
    int c = nc & (C - 1);
    int tid = threadIdx.x;

    if (tid < NBINS) {
        float s = bsum_in[tid * C + c];
        float q = bsq_in [tid * C + c];
#pragma unroll
        for (int m = NBINS / 2; m >= 1; m >>= 1) { s += __shfl_xor(s, m); q += __shfl_xor(q, m); }
        if (tid == 0) {
            float mm  = s * invcnt_in;
            float var = fmaf(q, invcnt_in, -mm * mm);
            float is  = gamma[c] * rsqrtf(var + EPSV);
            bnss[0] = is; bnss[1] = fmaf(-mm, is, beta[c]);
        }
    }
    __syncthreads();
    float scv = bnss[0], shv = bnss[1];

    const u16* pl = t + (size_t)nc * HW;
    float s = 0.f;
    for (int p = tid * 8; p < HW; p += 2048) {
        ush8 v = *(const ush8*)(pl + p);
#pragma unroll
        for (int i = 0; i < 8; i++) s += relu(fmaf(bf2f(v[i]), scv, shv));
    }
    int lane = tid & 63, wid = tid >> 6;
#pragma unroll
    for (int o = 32; o; o >>= 1) s += __shfl_down(s, o);
    if (lane == 0) red[wid] = s;
    __syncthreads();
    if (tid == 0) out[nc] = (red[0] + red[1] + red[2] + red[3]) * (1.f / HW);
}

extern "C" void kernel_launch(void* const* d_in, const int* in_sizes, int n_in,
                              void* d_out, int out_size, void* d_ws, size_t ws_size,
                              hipStream_t stream)
{
    const float* x = (const float*)d_in[0];
    const float* P[3][8];
    for (int b = 0; b < 3; b++)
        for (int j = 0; j < 8; j++)
            P[b][j] = (const float*)d_in[1 + b * 8 + j];

    float* ws = (float*)d_ws;
    float* stats = ws;                       // 6 stages * 2*NBINS*128 = 49152 f32
    u16*  wswz0  = (u16*)(stats + 49152);    // 2048 u16
    u16*  wswz1  = wswz0 + 2048;             // 8192 u16
    u16*  wswz2  = wswz1 + 8192;             // 16384 u16
    u16*  A      = wswz2 + 16384;            // up to 12,845,056 bf16
    u16*  B      = A + 13000000;             // up to 25,690,112 bf16

    float* out = (float*)d_out;

    prep_k<<<13, 256, 0, stream>>>(P[0][4], P[1][4], P[2][4], wswz0, wswz1, wswz2, stats);

#define BSUM(i) (stats + (i) * 8192)
#define BSQ(i)  (stats + (i) * 8192 + 4096)

    const float inv1 = 1.f / (32.f * 12544.f);
    const float inv2 = 1.f / (32.f * 3136.f);

    // ---- block 0: dw 32ch 112x112 (fp32 in) ; pw 32->64 ----
    dwlds_k<112, 32, false, 16, 120, float><<<7168, 256, 0, stream>>>(
        x, A, P[0][0], P[0][1], nullptr, nullptr, nullptr, nullptr, 0.f,
        BSUM(0), BSQ(0));

    pwmfma_k<32, 64, 12544><<<6272, 256, 0, stream>>>(
        A, B, wswz0, P[0][5], P[0][2], P[0][3], BSUM(0), BSQ(0), inv1,
        BSUM(1), BSQ(1));

    // ---- block 1: dw 64ch stride 2 112->56 (LDS-staged) ; pw 64->128 ----
    dwlds2_k<112, 56, 64><<<8192, 256, 0, stream>>>(
        B, A, P[1][0], P[1][1], P[0][6], P[0][7], BSUM(1), BSQ(1), inv1,
        BSUM(2), BSQ(2));

    pwmfma_k<64, 128, 3136><<<1568, 256, 0, stream>>>(
        A, B, wswz1, P[1][5], P[1][2], P[1][3], BSUM(2), BSQ(2), inv2,
        BSUM(3), BSQ(3));

    // ---- block 2: dw 128ch 56x56 ; pw 128->128 ----
    dwlds_k<56, 128, true, 28, 68, u16><<<8192, 256, 0, stream>>>(
        B, A, P[2][0], P[2][1], P[1][6], P[1][7], BSUM(3), BSQ(3), inv2,
        BSUM(4), BSQ(4));

    pwmfma_k<128, 128, 3136><<<1568, 256, 0, stream>>>(
        A, B, wswz2, P[2][5], P[2][2], P[2][3], BSUM(4), BSQ(4), inv2,
        BSUM(5), BSQ(5));

    // ---- final: BN+ReLU + global average pool ----
    avgpool_k<3136, 128><<<4096, 256, 0, stream>>>(
        B, P[2][6], P[2][7], BSUM(5), BSQ(5), inv2, out);

#undef BSUM
#undef BSQ
}

// Round 9
// 153.463 us; speedup vs baseline: 1.1893x; 1.1893x over previous
//
#include <hip/hip_runtime.h>

#define EPSV 1e-5f
#define NBINS 32

typedef unsigned short u16;
typedef unsigned int u32;
typedef __attribute__((ext_vector_type(4))) unsigned short ush4;
typedef __attribute__((ext_vector_type(8))) unsigned short ush8;
typedef __attribute__((ext_vector_type(8))) short short8;
typedef __attribute__((ext_vector_type(4))) float f32x4;

__device__ __forceinline__ float relu(float x) { return fmaxf(x, 0.f); }

__device__ __forceinline__ u16 f2bf(float f) {
    u32 u = __builtin_bit_cast(u32, f);
    u32 r = (u + 0x7fffu + ((u >> 16) & 1u)) >> 16;
    return (u16)r;
}
__device__ __forceinline__ float bf2f(u16 v) {
    return __builtin_bit_cast(float, (u32)v << 16);
}
// LDS quad swizzle: flip quad-bit0 from quad-bit3 (breaks even-orbit bank degeneracy)
__device__ __forceinline__ int swzq(int q) { return q ^ ((q >> 3) & 1); }

// ---- prep: zero stat bins + swizzle pw weights into fragment order ----
template<int CIN, int COUT>
__device__ __forceinline__ void prep_one(const float* __restrict__ w,
                                         u16* __restrict__ dst, int widx) {
    const int NT = COUT / 16;
    int lane = widx & 63;
    int t  = (widx >> 6) % NT;
    int ks = (widx >> 6) / NT;
    int co  = t * 16 + (lane & 15);
    int ci0 = ks * 32 + (lane >> 4) * 8;
#pragma unroll
    for (int i = 0; i < 8; i++)
        dst[(size_t)widx * 8 + i] = f2bf(w[co * CIN + ci0 + i]);
}

__global__ void prep_k(const float* __restrict__ w0, const float* __restrict__ w1,
                       const float* __restrict__ w2, u16* __restrict__ s0,
                       u16* __restrict__ s1, u16* __restrict__ s2,
                       float* __restrict__ bins) {
    int i = blockIdx.x * 256 + threadIdx.x;          // 3328 threads
    for (int z = i; z < 6 * 2 * NBINS * 128; z += 3328) bins[z] = 0.f;
    if (i < 256)       prep_one<32, 64>  (w0, s0, i);
    else if (i < 1280) prep_one<64, 128> (w1, s1, i - 256);
    else if (i < 3328) prep_one<128, 128>(w2, s2, i - 1280);
}

// ---- depthwise 3x3 pad 1 stride 1, LDS-staged band, swizzled quads ----
// Block = (plane, band of BR output rows). All LDS ops are float4 via swzq.
template<int IHW, int C, bool BNIN, int BR, int QPR, typename TIN>
__global__ __launch_bounds__(256) void dwlds_k(
    const TIN* __restrict__ in, u16* __restrict__ out,
    const float* __restrict__ w9, const float* __restrict__ bias,
    const float* __restrict__ gamma, const float* __restrict__ beta,
    const float* __restrict__ bsum_in, const float* __restrict__ bsq_in,
    float invcnt_in, float* __restrict__ bsum, float* __restrict__ bsq)
{
    constexpr bool F32 = sizeof(TIN) == 4;
    constexpr int NB  = IHW / BR;
    constexpr int TPR = IHW / 8;
    constexpr int NACT = BR * TPR;
    constexpr int W4 = IHW / 4;
    __shared__ float4 tile[(BR + 2) * QPR];
    __shared__ float redbuf[8];

    const int bid = blockIdx.x;
    const int plane = bid / NB;
    const int band  = bid % NB;
    const int c = plane & (C - 1);
    const int tid = threadIdx.x;

    // per-wave redundant BN finalize (no barrier, no LDS)
    float scv = 1.f, shv = 0.f;
    if (BNIN) {
        int lane = tid & 63;
        float s = 0.f, q = 0.f;
        if (lane < NBINS) { s = bsum_in[lane * C + c]; q = bsq_in[lane * C + c]; }
#pragma unroll
        for (int m = NBINS / 2; m >= 1; m >>= 1) { s += __shfl_xor(s, m); q += __shfl_xor(q, m); }
        s = __shfl(s, 0); q = __shfl(q, 0);
        float mm  = s * invcnt_in;
        float var = fmaf(q, invcnt_in, -mm * mm);
        scv = gamma[c] * rsqrtf(var + EPSV);
        shv = fmaf(-mm, scv, beta[c]);
    }

    const int r0 = band * BR;
    const TIN* base = in + (size_t)plane * (IHW * IHW);

    // zero left/right pad quads
    for (int i = tid; i < (BR + 2) * 2; i += 256) {
        int r = i >> 1, side = i & 1;
        tile[swzq(r * QPR + side * (W4 + 1))] = float4{0.f, 0.f, 0.f, 0.f};
    }
    // stage rows r0-1 .. r0+BR with BN+ReLU (halo rows = 0)
    for (int i = tid; i < (BR + 2) * W4; i += 256) {
        int r = i / W4, c4 = (i % W4) * 4;
        int gr = r0 - 1 + r;
        float4 v = {0.f, 0.f, 0.f, 0.f};
        if (gr >= 0 && gr < IHW) {
            if constexpr (F32) {
                v = *(const float4*)(base + (size_t)gr * IHW + c4);
            } else {
                ush4 h = *(const ush4*)(base + (size_t)gr * IHW + c4);
                v = {bf2f(h[0]), bf2f(h[1]), bf2f(h[2]), bf2f(h[3])};
            }
            if (BNIN) {
                v.x = relu(fmaf(v.x, scv, shv)); v.y = relu(fmaf(v.y, scv, shv));
                v.z = relu(fmaf(v.z, scv, shv)); v.w = relu(fmaf(v.w, scv, shv));
            }
        }
        tile[swzq(r * QPR + 1 + (c4 >> 2))] = v;
    }
    __syncthreads();

    float s = 0.f, q = 0.f;
    if (tid < NACT) {
        const int r = tid / TPR;
        const int k = tid % TPR;
        float wv[9];
#pragma unroll
        for (int kk = 0; kk < 9; kk++) wv[kk] = w9[c * 9 + kk];
        float bz = bias[c];
        float a[8];
#pragma unroll
        for (int j = 0; j < 8; j++) a[j] = bz;
#pragma unroll
        for (int kr = 0; kr < 3; kr++) {
            int qb = (r + kr) * QPR + 2 * k;
            float4 va = tile[swzq(qb)];
            float4 vb = tile[swzq(qb + 1)];
            float4 vc = tile[swzq(qb + 2)];
            float4 vd = tile[swzq(qb + 3)];
            float sq[10] = {va.w, vb.x, vb.y, vb.z, vb.w, vc.x, vc.y, vc.z, vc.w, vd.x};
            float k0 = wv[kr * 3], k1 = wv[kr * 3 + 1], k2 = wv[kr * 3 + 2];
#pragma unroll
            for (int j = 0; j < 8; j++)
                a[j] = fmaf(k0, sq[j], fmaf(k1, sq[j + 1], fmaf(k2, sq[j + 2], a[j])));
        }
        u16* ob = out + (size_t)plane * (IHW * IHW) + (size_t)(r0 + r) * IHW + k * 8;
        ush4 o0 = {f2bf(a[0]), f2bf(a[1]), f2bf(a[2]), f2bf(a[3])};
        ush4 o1 = {f2bf(a[4]), f2bf(a[5]), f2bf(a[6]), f2bf(a[7])};
        *(ush4*)ob = o0;
        *(ush4*)(ob + 4) = o1;
#pragma unroll
        for (int j = 0; j < 8; j++) { s += a[j]; q = fmaf(a[j], a[j], q); }
    }
#pragma unroll
    for (int m = 32; m >= 1; m >>= 1) { s += __shfl_xor(s, m); q += __shfl_xor(q, m); }
    int lane = tid & 63, wid = tid >> 6;
    if (lane == 0) { redbuf[wid] = s; redbuf[4 + wid] = q; }
    __syncthreads();
    if (tid == 0) {
        s = redbuf[0] + redbuf[1] + redbuf[2] + redbuf[3];
        q = redbuf[4] + redbuf[5] + redbuf[6] + redbuf[7];
        unsigned bin = bid & (NBINS - 1);
        atomicAdd(&bsum[bin * C + c], s);
        atomicAdd(&bsq [bin * C + c], q);
    }
}

// ---- depthwise 3x3 pad 1 STRIDE 2, LDS-staged band, swizzled quads ----
template<int IHW, int OHW, int C>
__global__ __launch_bounds__(256) void dwlds2_k(
    const u16* __restrict__ in, u16* __restrict__ out,
    const float* __restrict__ w9, const float* __restrict__ bias,
    const float* __restrict__ gamma, const float* __restrict__ beta,
    const float* __restrict__ bsum_in, const float* __restrict__ bsq_in,
    float invcnt_in, float* __restrict__ bsum, float* __restrict__ bsq)
{
    constexpr int BRO = 14;
    constexpr int NB  = OHW / BRO;
    constexpr int NIR = 2 * BRO + 1;        // 29 staged input rows
    constexpr int QPR = 30;                 // quads per row (120 floats)
    constexpr int CT  = OHW / 4;
    constexpr int NACT = BRO * CT;
    constexpr int W4 = IHW / 4;
    __shared__ float4 tile[NIR * QPR];
    __shared__ float redbuf[8];

    const int bid = blockIdx.x;
    const int plane = bid / NB;
    const int band  = bid % NB;
    const int c = plane & (C - 1);
    const int tid = threadIdx.x;

    // per-wave redundant BN finalize
    float scv, shv;
    {
        int lane = tid & 63;
        float s = 0.f, q = 0.f;
        if (lane < NBINS) { s = bsum_in[lane * C + c]; q = bsq_in[lane * C + c]; }
#pragma unroll
        for (int m = NBINS / 2; m >= 1; m >>= 1) { s += __shfl_xor(s, m); q += __shfl_xor(q, m); }
        s = __shfl(s, 0); q = __shfl(q, 0);
        float mm  = s * invcnt_in;
        float var = fmaf(q, invcnt_in, -mm * mm);
        scv = gamma[c] * rsqrtf(var + EPSV);
        shv = fmaf(-mm, scv, beta[c]);
    }

    const int r0 = band * BRO;
    const u16* base = in + (size_t)plane * (IHW * IHW);

    for (int i = tid; i < NIR; i += 256)
        tile[swzq(i * QPR)] = float4{0.f, 0.f, 0.f, 0.f};
    for (int i = tid; i < NIR * W4; i += 256) {
        int lr = i / W4, c4 = (i % W4) * 4;
        int gr = 2 * r0 - 1 + lr;
        float4 v = {0.f, 0.f, 0.f, 0.f};
        if (gr >= 0 && gr < IHW) {
            ush4 h = *(const ush4*)(base + (size_t)gr * IHW + c4);
            v.x = relu(fmaf(bf2f(h[0]), scv, shv));
            v.y = relu(fmaf(bf2f(h[1]), scv, shv));
            v.z = relu(fmaf(bf2f(h[2]), scv, shv));
            v.w = relu(fmaf(bf2f(h[3]), scv, shv));
        }
        tile[swzq(lr * QPR + 1 + (c4 >> 2))] = v;
    }
    __syncthreads();

    float s = 0.f, q = 0.f;
    if (tid < NACT) {
        const int r  = tid / CT;
        const int ct = tid % CT;
        float wv[9];
#pragma unroll
        for (int k = 0; k < 9; k++) wv[k] = w9[c * 9 + k];
        float bz = bias[c];
        float a[4] = {bz, bz, bz, bz};
#pragma unroll
        for (int kr = 0; kr < 3; kr++) {
            int qb = (2 * r + kr) * QPR + 2 * ct;
            float4 va = tile[swzq(qb)];
            float4 vb = tile[swzq(qb + 1)];
            float4 vc = tile[swzq(qb + 2)];
            float sq[9] = {va.w, vb.x, vb.y, vb.z, vb.w, vc.x, vc.y, vc.z, vc.w};
            float k0 = wv[kr * 3], k1 = wv[kr * 3 + 1], k2 = wv[kr * 3 + 2];
#pragma unroll
            for (int cc = 0; cc < 4; cc++)
                a[cc] = fmaf(k0, sq[2 * cc], fmaf(k1, sq[2 * cc + 1],
                            fmaf(k2, sq[2 * cc + 2], a[cc])));
        }
        u16* ob = out + (size_t)plane * (OHW * OHW) + (size_t)(r0 + r) * OHW + 4 * ct;
        ush4 o = {f2bf(a[0]), f2bf(a[1]), f2bf(a[2]), f2bf(a[3])};
        *(ush4*)ob = o;
#pragma unroll
        for (int j = 0; j < 4; j++) { s += a[j]; q = fmaf(a[j], a[j], q); }
    }
#pragma unroll
    for (int m = 32; m >= 1; m >>= 1) { s += __shfl_xor(s, m); q += __shfl_xor(q, m); }
    int lane = tid & 63, wid = tid >> 6;
    if (lane == 0) { redbuf[wid] = s; redbuf[4 + wid] = q; }
    __syncthreads();
    if (tid == 0) {
        s = redbuf[0] + redbuf[1] + redbuf[2] + redbuf[3];
        q = redbuf[4] + redbuf[5] + redbuf[6] + redbuf[7];
        unsigned bin = bid & (NBINS - 1);
        atomicAdd(&bsum[bin * C + c], s);
        atomicAdd(&bsq [bin * C + c], q);
    }
}

// ---- pointwise 1x1 conv via bf16 MFMA (X=A, W=B), folded finalize + stats ----
template<int CIN, int COUT, int HW>
__global__ __launch_bounds__(256, 4) void pwmfma_k(
    const u16* __restrict__ in, u16* __restrict__ out,
    const u16* __restrict__ wswz, const float* __restrict__ bias,
    const float* __restrict__ gamma, const float* __restrict__ beta,
    const float* __restrict__ bsum_in, const float* __restrict__ bsq_in,
    float invcnt_in, float* __restrict__ bsum, float* __restrict__ bsq)
{
    constexpr int NK = CIN / 32;
    constexpr int NT = COUT / 16;
    constexpr int ROWSTRIDE = NK * 512 + 8;
    __shared__ u16 frag[4 * ROWSTRIDE];
    __shared__ float lsum[4 * COUT];
    __shared__ float lsq [4 * COUT];
    __shared__ float scs[CIN], shs[CIN];

    const int tid = threadIdx.x;

    if (tid < CIN) {
        float s = 0.f, q = 0.f;
        for (int b = 0; b < NBINS; b++) {
            s += bsum_in[b * CIN + tid];
            q += bsq_in [b * CIN + tid];
        }
        float mm  = s * invcnt_in;
        float var = fmaf(q, invcnt_in, -mm * mm);
        float is  = gamma[tid] * rsqrtf(var + EPSV);
        scs[tid] = is; shs[tid] = fmaf(-mm, is, beta[tid]);
    }
    __syncthreads();

    const size_t pixbase = (size_t)blockIdx.x * 64;   // HW % 64 == 0
    const int n  = (int)(pixbase / HW);
    const int p0 = (int)(pixbase % HW);

    {
        const int px = tid & 63;
        const int kq = tid >> 6;
        const u16* ipx = in + (size_t)n * CIN * HW + p0 + px;
#pragma unroll
        for (int ks = 0; ks < NK; ks++) {
            const int ci0 = (ks * 4 + kq) * 8;
            short8 pkd;
#pragma unroll
            for (int j = 0; j < 8; j++) {
                float v = relu(fmaf(bf2f(ipx[(size_t)(ci0 + j) * HW]), scs[ci0 + j], shs[ci0 + j]));
                pkd[j] = (short)f2bf(v);
            }
            *(short8*)&frag[(size_t)(px >> 4) * ROWSTRIDE + ks * 512 + ((px & 15) + 16 * kq) * 8] = pkd;
        }
    }
    __syncthreads();

    const int wv   = tid >> 6;
    const int lane = tid & 63;
    f32x4 acc[NT];
#pragma unroll
    for (int t = 0; t < NT; t++) acc[t] = (f32x4){0.f, 0.f, 0.f, 0.f};

    const short8* wp = (const short8*)wswz;
#pragma unroll
    for (int ks = 0; ks < NK; ks++) {
        short8 af = *(const short8*)&frag[(size_t)wv * ROWSTRIDE + ks * 512 + lane * 8];
#pragma unroll
        for (int t = 0; t < NT; t++) {
            short8 bf = wp[(ks * NT + t) * 64 + lane];
            acc[t] = __builtin_amdgcn_mfma_f32_16x16x32_bf16(af, bf, acc[t], 0, 0, 0);
        }
    }

    const int col  = lane & 15;
    const int prow = (lane >> 4) * 4;
    const int p    = p0 + wv * 16 + prow;
#pragma unroll
    for (int t = 0; t < NT; t++) {
        int co = t * 16 + col;
        float bz = bias[co];
        float v0 = acc[t][0] + bz, v1 = acc[t][1] + bz;
        float v2 = acc[t][2] + bz, v3 = acc[t][3] + bz;
        ush4 o = {f2bf(v0), f2bf(v1), f2bf(v2), f2bf(v3)};
        *(ush4*)(out + ((size_t)n * COUT + co) * HW + p) = o;
        float s = (v0 + v1) + (v2 + v3);
        float q = fmaf(v0, v0, fmaf(v1, v1, fmaf(v2, v2, v3 * v3)));
        s += __shfl_xor(s, 16); q += __shfl_xor(q, 16);
        s += __shfl_xor(s, 32); q += __shfl_xor(q, 32);
        if (lane < 16) { lsum[wv * COUT + co] = s; lsq[wv * COUT + co] = q; }
    }
    __syncthreads();
    if (tid < COUT) {
        const unsigned bin = blockIdx.x & (NBINS - 1);
        float s = lsum[tid] + lsum[COUT + tid] + lsum[2 * COUT + tid] + lsum[3 * COUT + tid];
        float q = lsq[tid]  + lsq[COUT + tid]  + lsq[2 * COUT + tid]  + lsq[3 * COUT + tid];
        atomicAdd(&bsum[bin * COUT + tid], s);
        atomicAdd(&bsq [bin * COUT + tid], q);
    }
}

// ---- final: per-wave folded finalize + BN+ReLU + global average pool ----
template<int HW, int C>
__global__ __launch_bounds__(256) void avgpool_k(
    const u16* __restrict__ t,
    const float* __restrict__ gamma, const float* __restrict__ beta,
    const float* __restrict__ bsum_in, const float* __restrict__ bsq_in,
    float invcnt_in, float* __restrict__ out)
{
    __shared__ float red[4];
    int nc = blockIdx.x;
    int c = nc & (C - 1);
    int tid = threadIdx.x;

    float scv, shv;
    {
        int lane = tid & 63;
        float s = 0.f, q = 0.f;
        if (lane < NBINS) { s = bsum_in[lane * C + c]; q = bsq_in[lane * C + c]; }
#pragma unroll
        for (int m = NBINS / 2; m >= 1; m >>= 1) { s += __shfl_xor(s, m); q += __shfl_xor(q, m); }
        s = __shfl(s, 0); q = __shfl(q, 0);
        float mm  = s * invcnt_in;
        float var = fmaf(q, invcnt_in, -mm * mm);
        scv = gamma[c] * rsqrtf(var + EPSV);
        shv = fmaf(-mm, scv, beta[c]);
    }

    const u16* pl = t + (size_t)nc * HW;
    float s = 0.f;
    for (int p = tid * 8; p < HW; p += 2048) {
        ush8 v = *(const ush8*)(pl + p);
#pragma unroll
        for (int i = 0; i < 8; i++) s += relu(fmaf(bf2f(v[i]), scv, shv));
    }
    int lane = tid & 63, wid = tid >> 6;
#pragma unroll
    for (int o = 32; o; o >>= 1) s += __shfl_down(s, o);
    if (lane == 0) red[wid] = s;
    __syncthreads();
    if (tid == 0) out[nc] = (red[0] + red[1] + red[2] + red[3]) * (1.f / HW);
}

extern "C" void kernel_launch(void* const* d_in, const int* in_sizes, int n_in,
                              void* d_out, int out_size, void* d_ws, size_t ws_size,
                              hipStream_t stream)
{
    const float* x = (const float*)d_in[0];
    const float* P[3][8];
    for (int b = 0; b < 3; b++)
        for (int j = 0; j < 8; j++)
            P[b][j] = (const float*)d_in[1 + b * 8 + j];

    float* ws = (float*)d_ws;
    float* stats = ws;                       // 6 stages * 2*NBINS*128 = 49152 f32
    u16*  wswz0  = (u16*)(stats + 49152);    // 2048 u16
    u16*  wswz1  = wswz0 + 2048;             // 8192 u16
    u16*  wswz2  = wswz1 + 8192;             // 16384 u16
    u16*  A      = wswz2 + 16384;            // up to 12,845,056 bf16
    u16*  B      = A + 13000000;             // up to 25,690,112 bf16

    float* out = (float*)d_out;

    prep_k<<<13, 256, 0, stream>>>(P[0][4], P[1][4], P[2][4], wswz0, wswz1, wswz2, stats);

#define BSUM(i) (stats + (i) * 8192)
#define BSQ(i)  (stats + (i) * 8192 + 4096)

    const float inv1 = 1.f / (32.f * 12544.f);
    const float inv2 = 1.f / (32.f * 3136.f);

    // ---- block 0: dw 32ch 112x112 (fp32 in) ; pw 32->64 ----
    dwlds_k<112, 32, false, 16, 30, float><<<7168, 256, 0, stream>>>(
        x, A, P[0][0], P[0][1], nullptr, nullptr, nullptr, nullptr, 0.f,
        BSUM(0), BSQ(0));

    pwmfma_k<32, 64, 12544><<<6272, 256, 0, stream>>>(
        A, B, wswz0, P[0][5], P[0][2], P[0][3], BSUM(0), BSQ(0), inv1,
        BSUM(1), BSQ(1));

    // ---- block 1: dw 64ch stride 2 112->56 ; pw 64->128 ----
    dwlds2_k<112, 56, 64><<<8192, 256, 0, stream>>>(
        B, A, P[1][0], P[1][1], P[0][6], P[0][7], BSUM(1), BSQ(1), inv1,
        BSUM(2), BSQ(2));

    pwmfma_k<64, 128, 3136><<<1568, 256, 0, stream>>>(
        A, B, wswz1, P[1][5], P[1][2], P[1][3], BSUM(2), BSQ(2), inv2,
        BSUM(3), BSQ(3));

    // ---- block 2: dw 128ch 56x56 ; pw 128->128 ----
    dwlds_k<56, 128, true, 28, 17, u16><<<8192, 256, 0, stream>>>(
        B, A, P[2][0], P[2][1], P[1][6], P[1][7], BSUM(3), BSQ(3), inv2,
        BSUM(4), BSQ(4));

    pwmfma_k<128, 128, 3136><<<1568, 256, 0, stream>>>(
        A, B, wswz2, P[2][5], P[2][2], P[2][3], BSUM(4), BSQ(4), inv2,
        BSUM(5), BSQ(5));

    // ---- final: BN+ReLU + global average pool ----
    avgpool_k<3136, 128><<<4096, 256, 0, stream>>>(
        B, P[2][6], P[2][7], BSUM(5), BSQ(5), inv2, out);

#undef BSUM
#undef BSQ
}